// Round 13
// baseline (266.419 us; speedup 1.0000x reference)
//
#include <hip/hip_runtime.h>
#include <hip/hip_bf16.h>

#define BATCH 16
#define NNODE 2000
#define HDIM  128
#define KNN   5
#define NROWS (BATCH * NNODE)   // 32000
#define NTILE (NROWS / 16)      // 2000
#define LGRID 768               // persistent grid; 768 % 8 == 0; <= 1024 capacity
#define LN_EPS 1e-5f

typedef __attribute__((ext_vector_type(8))) short short8;
typedef __attribute__((ext_vector_type(4))) float f32x4;

__device__ __forceinline__ float b2f(short s) {
    unsigned int u = ((unsigned int)(unsigned short)s) << 16;
    return __uint_as_float(u);
}
__device__ __forceinline__ short f2b(float f) {
    __hip_bfloat16 h = __float2bfloat16(f);
    return *reinterpret_cast<short*>(&h);
}

__device__ __forceinline__ unsigned long long pack_di(float v, unsigned int idx) {
    unsigned int b = __float_as_uint(v);
    b = (b & 0x80000000u) ? ~b : (b | 0x80000000u);   // order-preserving
    return ((unsigned long long)b << 32) | idx;
}

// ---------------------------------------------------------------------------
// Kernel 1: knn + softmax (8000 blocks, one wave per row). Folded preps:
// (a) Ws -> bf16 MFMA B-fragment order WB; (b) node_emb -> bf16 hb;
// (c) zero the global-barrier counters for kernel 2 (replay-safe).
// ---------------------------------------------------------------------------
__global__ __launch_bounds__(256) void knn_prep_kernel(
    const float* __restrict__ dist,
    const float* __restrict__ Ws,
    const float* __restrict__ node_emb,
    __hip_bfloat16* __restrict__ WB,
    short* __restrict__ hb,
    int* __restrict__ w_idx,
    float* __restrict__ w_val,
    unsigned int* __restrict__ barrier_ctr)
{
    int tg = blockIdx.x * 256 + threadIdx.x;

    if (tg < 4) {   // (c) barrier counters
        __hip_atomic_store(&barrier_ctr[tg], 0u, __ATOMIC_RELAXED,
                           __HIP_MEMORY_SCOPE_AGENT);
    }

    // ---- (a) weight prep: 6144 short8 entries
    if (tg < 3 * 2048) {
        int l    = tg >> 11;
        int r    = tg & 2047;
        int lane = r & 63;
        int ks   = (r >> 6) & 3;
        int ct   = (r >> 8) & 1;
        int wv   = (r >> 9) & 3;
        int col  = wv * 32 + ct * 16 + (lane & 15);
        int k0   = ks * 32 + (lane >> 4) * 8;
        const float* src = Ws + ((size_t)l << 14) + col * HDIM + k0;
        __hip_bfloat16* dst = WB + ((size_t)tg << 3);
        #pragma unroll
        for (int e = 0; e < 8; ++e) dst[e] = __float2bfloat16(src[e]);
    }

    // ---- (b) node_emb -> bf16: 512000 groups of 8
    if (tg < NROWS * HDIM / 8) {
        const float4* src = reinterpret_cast<const float4*>(node_emb) + tg * 2;
        float4 a = src[0], bq = src[1];
        short8 pk;
        pk[0]=f2b(a.x); pk[1]=f2b(a.y); pk[2]=f2b(a.z); pk[3]=f2b(a.w);
        pk[4]=f2b(bq.x); pk[5]=f2b(bq.y); pk[6]=f2b(bq.z); pk[7]=f2b(bq.w);
        *reinterpret_cast<short8*>(hb + (size_t)tg * 8) = pk;
    }

    // ---- knn for this wave's row
    int row  = blockIdx.x * 4 + (threadIdx.x >> 6);
    int lane = threadIdx.x & 63;
    const float4* r4 = reinterpret_cast<const float4*>(dist + (size_t)row * NNODE);

    unsigned long long pk0 = ~0ull, pk1 = ~0ull, pk2 = ~0ull, pk3 = ~0ull, pk4 = ~0ull;

    auto ins = [&](float d, int m) {
        unsigned long long key = pack_di(d, (unsigned int)m);
        if (key < pk4) {
            pk4 = key;
            unsigned long long t;
            if (pk4 < pk3) { t = pk3; pk3 = pk4; pk4 = t; }
            if (pk3 < pk2) { t = pk2; pk2 = pk3; pk3 = t; }
            if (pk2 < pk1) { t = pk1; pk1 = pk2; pk2 = t; }
            if (pk1 < pk0) { t = pk0; pk0 = pk1; pk1 = t; }
        }
    };

    float4 v[8];
    int base7 = lane + 448;
    bool has8 = base7 < (NNODE / 4);
    #pragma unroll
    for (int i = 0; i < 7; ++i) v[i] = r4[lane + 64 * i];
    v[7] = r4[has8 ? base7 : lane];

    #pragma unroll
    for (int i = 0; i < 7; ++i) {
        int base = (lane + 64 * i) * 4;
        ins(v[i].x, base); ins(v[i].y, base + 1);
        ins(v[i].z, base + 2); ins(v[i].w, base + 3);
    }
    if (has8) {
        int base = base7 * 4;
        ins(v[7].x, base); ins(v[7].y, base + 1);
        ins(v[7].z, base + 2); ins(v[7].w, base + 3);
    }

    unsigned long long chosen[KNN];
    #pragma unroll
    for (int r = 0; r < KNN; ++r) {
        unsigned long long mn = pk0;
        #pragma unroll
        for (int off = 32; off; off >>= 1) {
            unsigned long long o = __shfl_xor(mn, off, 64);
            if (o < mn) mn = o;
        }
        if (pk0 == mn) { pk0 = pk1; pk1 = pk2; pk2 = pk3; pk3 = pk4; pk4 = ~0ull; }
        chosen[r] = mn;
    }

    if (lane == 0) {
        float d[KNN]; int ix[KNN];
        #pragma unroll
        for (int r = 0; r < KNN; ++r) {
            unsigned int ub = (unsigned int)(chosen[r] >> 32);
            ub = (ub & 0x80000000u) ? (ub ^ 0x80000000u) : ~ub;
            d[r]  = __uint_as_float(ub);
            ix[r] = (int)(chosen[r] & 0xffffffffu);
        }
        float e[KNN]; float sum = 0.f;
        #pragma unroll
        for (int r = 0; r < KNN; ++r) { e[r] = expf(d[0] - d[r]); sum += e[r]; }
        float inv = 1.f / sum;
        #pragma unroll
        for (int r = 0; r < KNN; ++r) {
            w_idx[row * KNN + r] = ix[r];
            w_val[row * KNN + r] = e[r] * inv;
        }
    }
}

// ---------------------------------------------------------------------------
// Kernel 2 (persistent): all 3 GCN layers in ONE dispatch.
// 768 blocks x 256 threads, grid-stride over 2000 tiles per layer; manual
// device-scope barrier between layers (per-layer counter slot; counters
// zeroed by kernel 1 each call). Co-residency: __launch_bounds__(256,4)
// -> <=128 VGPR -> 4 blocks/CU x 256 CU = 1024 >= 768; LDS 9.8 KB.
// 768 % 8 == 0 keeps each block's tiles on one XCD (L2 slab locality).
// ---------------------------------------------------------------------------
__global__ __launch_bounds__(256, 4) void gcn_layers_kernel(
    const short* __restrict__ hb,            // bf16 h0
    const int*   __restrict__ w_idx,
    const float* __restrict__ w_val,
    const __hip_bfloat16* __restrict__ WB,   // 3 layers, fragment-ordered
    const float* __restrict__ bs,
    const float* __restrict__ gammas,
    const float* __restrict__ betas,
    short* __restrict__ h1b,
    short* __restrict__ h2b,
    float* __restrict__ out,
    unsigned int* __restrict__ barrier_ctr)
{
    __shared__ __hip_bfloat16 aggb[16][HDIM];   // 4 KB
    __shared__ short hown[16][HDIM];            // 4 KB
    __shared__ int   sidx[16][KNN];
    __shared__ float sw[16][KNN];
    __shared__ float wred[4][16][2];

    int tid = threadIdx.x;
    int wv  = tid >> 6;
    int l   = tid & 63;

    for (int layer = 0; layer < 3; ++layer) {
        const short* hin = (layer == 0) ? hb : (layer == 1) ? h1b : h2b;
        short* houtb     = (layer == 0) ? h1b : h2b;     // unused when layer==2
        const float* bias  = bs     + layer * HDIM;
        const float* gamma = gammas + layer * HDIM;
        const float* beta  = betas  + layer * HDIM;

        // B fragments for this layer: 8 coalesced short8 loads per wave
        const short8* wb = reinterpret_cast<const short8*>(WB) + (size_t)layer * 2048;
        short8 bfrag[2][4];
        #pragma unroll
        for (int ct = 0; ct < 2; ++ct)
            #pragma unroll
            for (int ks = 0; ks < 4; ++ks)
                bfrag[ct][ks] = wb[((wv * 2 + ct) * 4 + ks) * 64 + l];

        for (int t = blockIdx.x; t < NTILE; t += LGRID) {
            // XCD swizzle: x = t&7 is constant per block (LGRID % 8 == 0)
            int x   = t & 7;
            int j   = t >> 3;
            int hi  = (j >= 125);
            int bsw = 2 * x + hi;
            int gid = bsw * 125 + (j - hi * 125);
            int node0 = gid * 16;
            size_t hbase = (size_t)bsw * NNODE * HDIM;

            if (tid < 16 * KNN) {
                int m = tid / KNN, k = tid % KNN;
                sidx[m][k] = w_idx[(node0 + m) * KNN + k];
                sw[m][k]   = w_val[(node0 + m) * KNN + k];
            }
            __syncthreads();

            // gather (bf16, one short8 per neighbor) + own-row staging
            {
                int m  = tid >> 4;
                int c0 = (tid & 15) * 8;
                short8 own = *reinterpret_cast<const short8*>(
                    hin + (size_t)(node0 + m) * HDIM + c0);
                *reinterpret_cast<short8*>(&hown[m][c0]) = own;

                float a0=0,a1=0,a2=0,a3=0,a4=0,a5=0,a6=0,a7=0;
                #pragma unroll
                for (int k = 0; k < KNN; ++k) {
                    float wk = sw[m][k];
                    short8 hv = *reinterpret_cast<const short8*>(
                        hin + hbase + (size_t)sidx[m][k] * HDIM + c0);
                    a0 = fmaf(wk, b2f(hv[0]), a0); a1 = fmaf(wk, b2f(hv[1]), a1);
                    a2 = fmaf(wk, b2f(hv[2]), a2); a3 = fmaf(wk, b2f(hv[3]), a3);
                    a4 = fmaf(wk, b2f(hv[4]), a4); a5 = fmaf(wk, b2f(hv[5]), a5);
                    a6 = fmaf(wk, b2f(hv[6]), a6); a7 = fmaf(wk, b2f(hv[7]), a7);
                }
                short8 pk;
                pk[0]=f2b(a0); pk[1]=f2b(a1); pk[2]=f2b(a2); pk[3]=f2b(a3);
                pk[4]=f2b(a4); pk[5]=f2b(a5); pk[6]=f2b(a6); pk[7]=f2b(a7);
                *reinterpret_cast<short8*>(&aggb[m][c0]) = pk;
            }
            __syncthreads();

            // MFMA: per wave, C(16x32) over 4 k-steps
            f32x4 acc0 = {0.f,0.f,0.f,0.f}, acc1 = {0.f,0.f,0.f,0.f};
            #pragma unroll
            for (int ks = 0; ks < 4; ++ks) {
                short8 afrag = *reinterpret_cast<const short8*>(
                    &aggb[l & 15][ks * 32 + (l >> 4) * 8]);
                acc0 = __builtin_amdgcn_mfma_f32_16x16x32_bf16(afrag, bfrag[0][ks], acc0, 0, 0, 0);
                acc1 = __builtin_amdgcn_mfma_f32_16x16x32_bf16(afrag, bfrag[1][ks], acc1, 0, 0, 0);
            }

            // epilogue: y = h + relu(C + bias); LN over 128 cols
            int g = l >> 4;
            int col0 = wv * 32 + (l & 15);
            int col1 = col0 + 16;
            float b0  = bias[col0],  b1  = bias[col1];
            float gm0 = gamma[col0], gm1 = gamma[col1];
            float bt0 = beta[col0],  bt1 = beta[col1];

            float y0[4], y1[4];
            #pragma unroll
            for (int r = 0; r < 4; ++r) {
                int rl = g * 4 + r;
                y0[r] = b2f(hown[rl][col0]) + fmaxf(acc0[r] + b0, 0.f);
                y1[r] = b2f(hown[rl][col1]) + fmaxf(acc1[r] + b1, 0.f);
            }

            #pragma unroll
            for (int r = 0; r < 4; ++r) {
                float ss = y0[r] + y1[r];
                float qq = y0[r] * y0[r] + y1[r] * y1[r];
                #pragma unroll
                for (int off = 1; off < 16; off <<= 1) {
                    ss += __shfl_xor(ss, off, 64);
                    qq += __shfl_xor(qq, off, 64);
                }
                if ((l & 15) == 0) { wred[wv][g * 4 + r][0] = ss; wred[wv][g * 4 + r][1] = qq; }
            }
            __syncthreads();

            #pragma unroll
            for (int r = 0; r < 4; ++r) {
                int row = g * 4 + r;
                float S = wred[0][row][0] + wred[1][row][0] + wred[2][row][0] + wred[3][row][0];
                float Q = wred[0][row][1] + wred[1][row][1] + wred[2][row][1] + wred[3][row][1];
                float mu  = S * (1.f / 128.f);
                float var = Q * (1.f / 128.f) - mu * mu;
                float rs  = rsqrtf(var + LN_EPS);
                size_t orow = (size_t)(node0 + row) * HDIM;
                float o0 = (y0[r] - mu) * rs * gm0 + bt0;
                float o1 = (y1[r] - mu) * rs * gm1 + bt1;
                if (layer == 2) {
                    out[orow + col0] = o0;
                    out[orow + col1] = o1;
                } else {
                    houtb[orow + col0] = f2b(o0);
                    houtb[orow + col1] = f2b(o1);
                }
            }
            __syncthreads();   // protect sidx/sw/hown reuse next tile
        }

        // ---- device-scope global barrier between layers (not after last)
        if (layer < 2) {
            __syncthreads();
            if (tid == 0) {
                // release: make this block's h writes device-visible
                __hip_atomic_fetch_add(&barrier_ctr[layer], 1u,
                                       __ATOMIC_ACQ_REL, __HIP_MEMORY_SCOPE_AGENT);
                while (__hip_atomic_load(&barrier_ctr[layer], __ATOMIC_ACQUIRE,
                                         __HIP_MEMORY_SCOPE_AGENT) < (unsigned)LGRID) {
                    __builtin_amdgcn_s_sleep(8);
                }
            }
            __syncthreads();
        }
    }
}

// ---------------------------------------------------------------------------
extern "C" void kernel_launch(void* const* d_in, const int* in_sizes, int n_in,
                              void* d_out, int out_size, void* d_ws, size_t ws_size,
                              hipStream_t stream) {
    const float* node_emb = (const float*)d_in[0];
    const float* dist     = (const float*)d_in[1];
    const float* Ws       = (const float*)d_in[2];
    const float* bs       = (const float*)d_in[3];
    const float* gammas   = (const float*)d_in[4];
    const float* betas    = (const float*)d_in[5];
    float* out = (float*)d_out;

    char* ws = (char*)d_ws;
    int*   w_idx = (int*)  (ws + 0);                        // 640000 B
    float* w_val = (float*)(ws + 640000);                   // 640000 B
    __hip_bfloat16* WB = (__hip_bfloat16*)(ws + 1280000);   // 98304 B
    unsigned int* barrier_ctr = (unsigned int*)(ws + 1378304); // 16 B
    short* hb  = (short*)(ws + 1378320);                    // 8192000 B
    short* h1b = (short*)(ws + 9570320);                    // 8192000 B
    short* h2b = (short*)(ws + 17762320);                   // 8192000 B

    // Dispatch 1: knn + weight prep + node_emb->bf16 + barrier reset
    knn_prep_kernel<<<NROWS / 4, 256, 0, stream>>>(
        dist, Ws, node_emb, WB, hb, w_idx, w_val, barrier_ctr);

    // Dispatch 2: all three layers, persistent with manual global barrier
    gcn_layers_kernel<<<LGRID, 256, 0, stream>>>(
        hb, w_idx, w_val, WB, bs, gammas, betas, h1b, h2b, out, barrier_ctr);
}

// Round 14
// 125.426 us; speedup vs baseline: 2.1241x; 2.1241x over previous
//
#include <hip/hip_runtime.h>
#include <hip/hip_bf16.h>

#define BATCH 16
#define NNODE 2000
#define HDIM  128
#define KNN   5
#define NROWS (BATCH * NNODE)   // 32000
#define LN_EPS 1e-5f

typedef __attribute__((ext_vector_type(8))) short short8;
typedef __attribute__((ext_vector_type(4))) float f32x4;

__device__ __forceinline__ float b2f(short s) {
    unsigned int u = ((unsigned int)(unsigned short)s) << 16;
    return __uint_as_float(u);
}
__device__ __forceinline__ short f2b(float f) {
    __hip_bfloat16 h = __float2bfloat16(f);
    return *reinterpret_cast<short*>(&h);
}

__device__ __forceinline__ unsigned long long pack_di(float v, unsigned int idx) {
    unsigned int b = __float_as_uint(v);
    b = (b & 0x80000000u) ? ~b : (b | 0x80000000u);   // order-preserving
    return ((unsigned long long)b << 32) | idx;
}

// ---------------------------------------------------------------------------
// Kernel 1: fused knn + layer 0.
// 8000 blocks x 4 waves; wave wv does the FULL knn for row bid*4+wv exactly
// like the standalone kernel (same wave count, same 8-deep load batch ->
// same HBM queue depth). Then the block computes layer 0 for its own 4 rows:
// fp32 gathers from node_emb (input -> no cross-block dep), 16x16x32 MFMA
// with rows 4..15 zero-padded, LN epilogue, bf16 h1 output.
// Also packs Ws layers 1,2 -> WB fragments (consumed by later dispatches).
// ---------------------------------------------------------------------------
__global__ __launch_bounds__(256) void knn_l0_kernel(
    const float* __restrict__ dist,
    const float* __restrict__ node_emb,
    const float* __restrict__ Ws,
    const float* __restrict__ bias0,
    const float* __restrict__ gamma0,
    const float* __restrict__ beta0,
    __hip_bfloat16* __restrict__ WB,     // layers 1,2 fragment-packed
    int* __restrict__ w_idx,
    float* __restrict__ w_val,
    short* __restrict__ h1b)             // bf16 h after layer 0
{
    __shared__ __hip_bfloat16 aggb[16][HDIM];   // 4 KB (rows 4..15 stay zero)
    __shared__ float hown[4][HDIM];             // 2 KB fp32 residual
    __shared__ int   sidx[4][KNN];
    __shared__ float sw[4][KNN];
    __shared__ float wred[4][4][2];

    int tid = threadIdx.x;
    int wv  = tid >> 6;
    int l   = tid & 63;
    int bid = blockIdx.x;
    int row   = bid * 4 + wv;            // this wave's knn row / node
    int node0 = bid * 4;                 // block's 4 nodes (never cross batch)
    int b     = node0 / NNODE;
    size_t hbase = (size_t)b * NNODE * HDIM;

    // ---- clear aggb (only rows 4..15 matter; clear all 4 KB)
    {
        short8 z = {0,0,0,0,0,0,0,0};
        reinterpret_cast<short8*>(&aggb[0][0])[tid] = z;
    }

    // ---- WB pack for layers 1,2 (blocks 0..15): 4096 short8 entries
    int tg = bid * 256 + tid;
    if (tg < 2 * 2048) {
        int lw   = 1 + (tg >> 11);       // source layer 1 or 2
        int r    = tg & 2047;
        int lane = r & 63;
        int ks   = (r >> 6) & 3;
        int ct   = (r >> 8) & 1;
        int wvv  = (r >> 9) & 3;
        int col  = wvv * 32 + ct * 16 + (lane & 15);
        int k0   = ks * 32 + (lane >> 4) * 8;
        const float* src = Ws + ((size_t)lw << 14) + col * HDIM + k0;
        __hip_bfloat16* dst = WB + ((size_t)tg << 3);
        #pragma unroll
        for (int e = 0; e < 8; ++e) dst[e] = __float2bfloat16(src[e]);
    }

    // ---- Phase 1: knn (identical structure to the measured 38 us kernel)
    {
        const float4* r4 = reinterpret_cast<const float4*>(dist + (size_t)row * NNODE);
        unsigned long long pk0=~0ull, pk1=~0ull, pk2=~0ull, pk3=~0ull, pk4=~0ull;

        auto ins = [&](float d, int m) {
            unsigned long long key = pack_di(d, (unsigned int)m);
            if (key < pk4) {
                pk4 = key;
                unsigned long long t;
                if (pk4 < pk3) { t = pk3; pk3 = pk4; pk4 = t; }
                if (pk3 < pk2) { t = pk2; pk2 = pk3; pk3 = t; }
                if (pk2 < pk1) { t = pk1; pk1 = pk2; pk2 = t; }
                if (pk1 < pk0) { t = pk0; pk0 = pk1; pk1 = t; }
            }
        };

        float4 v[8];
        int base7 = l + 448;
        bool has8 = base7 < (NNODE / 4);
        #pragma unroll
        for (int i = 0; i < 7; ++i) v[i] = r4[l + 64 * i];
        v[7] = r4[has8 ? base7 : l];

        #pragma unroll
        for (int i = 0; i < 7; ++i) {
            int base = (l + 64 * i) * 4;
            ins(v[i].x, base); ins(v[i].y, base + 1);
            ins(v[i].z, base + 2); ins(v[i].w, base + 3);
        }
        if (has8) {
            int base = base7 * 4;
            ins(v[7].x, base); ins(v[7].y, base + 1);
            ins(v[7].z, base + 2); ins(v[7].w, base + 3);
        }

        unsigned long long chosen[KNN];
        #pragma unroll
        for (int r = 0; r < KNN; ++r) {
            unsigned long long mn = pk0;
            #pragma unroll
            for (int off = 32; off; off >>= 1) {
                unsigned long long o = __shfl_xor(mn, off, 64);
                if (o < mn) mn = o;
            }
            if (pk0 == mn) { pk0 = pk1; pk1 = pk2; pk2 = pk3; pk3 = pk4; pk4 = ~0ull; }
            chosen[r] = mn;
        }

        if (l == 0) {
            float d[KNN]; int ix[KNN];
            #pragma unroll
            for (int r = 0; r < KNN; ++r) {
                unsigned int ub = (unsigned int)(chosen[r] >> 32);
                ub = (ub & 0x80000000u) ? (ub ^ 0x80000000u) : ~ub;
                d[r]  = __uint_as_float(ub);
                ix[r] = (int)(chosen[r] & 0xffffffffu);
            }
            float e[KNN]; float sum = 0.f;
            #pragma unroll
            for (int r = 0; r < KNN; ++r) { e[r] = expf(d[0] - d[r]); sum += e[r]; }
            float inv = 1.f / sum;
            #pragma unroll
            for (int r = 0; r < KNN; ++r) {
                float wt = e[r] * inv;
                sidx[wv][r] = ix[r];
                sw[wv][r]   = wt;
                w_idx[row * KNN + r] = ix[r];
                w_val[row * KNN + r] = wt;
            }
        }
    }
    __syncthreads();   // aggb clear done + sidx/sw visible

    // ---- Phase 2: layer 0 for rows node0..node0+3
    // gather: wave wv = its row; lane l covers cols 2l, 2l+1 (fp32 float2)
    {
        int c = 2 * l;
        float2 ow = *reinterpret_cast<const float2*>(
            node_emb + (size_t)row * HDIM + c);
        *reinterpret_cast<float2*>(&hown[wv][c]) = ow;

        float a0 = 0.f, a1 = 0.f;
        #pragma unroll
        for (int k = 0; k < KNN; ++k) {
            float wk = sw[wv][k];
            float2 hv = *reinterpret_cast<const float2*>(
                node_emb + hbase + (size_t)sidx[wv][k] * HDIM + c);
            a0 = fmaf(wk, hv.x, a0);
            a1 = fmaf(wk, hv.y, a1);
        }
        unsigned short u0 = (unsigned short)f2b(a0);
        unsigned short u1 = (unsigned short)f2b(a1);
        *reinterpret_cast<ushort2*>(&aggb[wv][c]) = make_ushort2(u0, u1);
    }

    // B fragments from fp32 Ws layer 0 (built while gathers are in flight)
    short8 bfrag[2][4];
    #pragma unroll
    for (int ct = 0; ct < 2; ++ct) {
        int col = wv * 32 + ct * 16 + (l & 15);
        const float* wp = Ws + col * HDIM + (l >> 4) * 8;
        #pragma unroll
        for (int ks = 0; ks < 4; ++ks) {
            float4 u0 = *reinterpret_cast<const float4*>(wp + ks * 32);
            float4 u1 = *reinterpret_cast<const float4*>(wp + ks * 32 + 4);
            short8 rfr;
            rfr[0]=f2b(u0.x); rfr[1]=f2b(u0.y); rfr[2]=f2b(u0.z); rfr[3]=f2b(u0.w);
            rfr[4]=f2b(u1.x); rfr[5]=f2b(u1.y); rfr[6]=f2b(u1.z); rfr[7]=f2b(u1.w);
            bfrag[ct][ks] = rfr;
        }
    }
    __syncthreads();

    // MFMA: wave wv computes rows 0..15 (only 0..3 valid) x cols wv*32..+31
    f32x4 acc0 = {0.f,0.f,0.f,0.f}, acc1 = {0.f,0.f,0.f,0.f};
    #pragma unroll
    for (int ks = 0; ks < 4; ++ks) {
        short8 afrag = *reinterpret_cast<const short8*>(
            &aggb[l & 15][ks * 32 + (l >> 4) * 8]);
        acc0 = __builtin_amdgcn_mfma_f32_16x16x32_bf16(afrag, bfrag[0][ks], acc0, 0, 0, 0);
        acc1 = __builtin_amdgcn_mfma_f32_16x16x32_bf16(afrag, bfrag[1][ks], acc1, 0, 0, 0);
    }

    // epilogue on lanes 0..15 (C/D rows 0..3 live in lanes 0..15, regs 0..3)
    float y0[4], y1[4];
    int col0 = wv * 32 + (l & 15);
    int col1 = col0 + 16;
    if (l < 16) {
        float b0  = bias0[col0],  b1  = bias0[col1];
        #pragma unroll
        for (int r = 0; r < 4; ++r) {
            y0[r] = hown[r][col0] + fmaxf(acc0[r] + b0, 0.f);
            y1[r] = hown[r][col1] + fmaxf(acc1[r] + b1, 0.f);
        }
        #pragma unroll
        for (int r = 0; r < 4; ++r) {
            float ss = y0[r] + y1[r];
            float qq = y0[r] * y0[r] + y1[r] * y1[r];
            #pragma unroll
            for (int off = 1; off < 16; off <<= 1) {
                ss += __shfl_xor(ss, off, 64);
                qq += __shfl_xor(qq, off, 64);
            }
            if (l == 0) { wred[wv][r][0] = ss; wred[wv][r][1] = qq; }
        }
    }
    __syncthreads();

    if (l < 16) {
        float gm0 = gamma0[col0], gm1 = gamma0[col1];
        float bt0 = beta0[col0],  bt1 = beta0[col1];
        #pragma unroll
        for (int r = 0; r < 4; ++r) {
            float S = wred[0][r][0] + wred[1][r][0] + wred[2][r][0] + wred[3][r][0];
            float Q = wred[0][r][1] + wred[1][r][1] + wred[2][r][1] + wred[3][r][1];
            float mu  = S * (1.f / 128.f);
            float var = Q * (1.f / 128.f) - mu * mu;
            float rs  = rsqrtf(var + LN_EPS);
            size_t orow = (size_t)(node0 + r) * HDIM;
            h1b[orow + col0] = f2b((y0[r] - mu) * rs * gm0 + bt0);
            h1b[orow + col1] = f2b((y1[r] - mu) * rs * gm1 + bt1);
        }
    }
}

// ---------------------------------------------------------------------------
// Kernel 2: one GCN layer via MFMA, bf16 h storage (round-12 structure).
// Block = 4 waves, 16 consecutive nodes (XCD-swizzled).
// ---------------------------------------------------------------------------
template<bool OUT_F32>
__global__ __launch_bounds__(256) void layer_kernel_b(
    const short* __restrict__ hin,           // bf16 h
    const int*   __restrict__ w_idx,
    const float* __restrict__ w_val,
    const __hip_bfloat16* __restrict__ WB,   // fragment-ordered, this layer
    const float* __restrict__ bias,
    const float* __restrict__ gamma,
    const float* __restrict__ beta,
    short* __restrict__ hout_b,
    float* __restrict__ hout_f)
{
    __shared__ __hip_bfloat16 aggb[16][HDIM];   // 4 KB
    __shared__ short hown[16][HDIM];            // 4 KB
    __shared__ int   sidx[16][KNN];
    __shared__ float sw[16][KNN];
    __shared__ float wred[4][16][2];

    int tid = threadIdx.x;
    int wv  = tid >> 6;
    int l   = tid & 63;

    // XCD swizzle: 2000 blocks = 8 XCDs x 250; 2 batches per XCD.
    int bid = blockIdx.x;
    int x   = bid & 7;
    int j   = bid >> 3;
    int hi  = (j >= 125);
    int bsw = 2 * x + hi;
    int gid = bsw * 125 + (j - hi * 125);

    int node0 = gid * 16;
    size_t hbase = (size_t)bsw * NNODE * HDIM;

    const short8* wb = reinterpret_cast<const short8*>(WB);
    short8 bfrag[2][4];
    #pragma unroll
    for (int ct = 0; ct < 2; ++ct)
        #pragma unroll
        for (int ks = 0; ks < 4; ++ks)
            bfrag[ct][ks] = wb[((wv * 2 + ct) * 4 + ks) * 64 + l];

    if (tid < 16 * KNN) {
        int m = tid / KNN, k = tid % KNN;
        sidx[m][k] = w_idx[(node0 + m) * KNN + k];
        sw[m][k]   = w_val[(node0 + m) * KNN + k];
    }
    __syncthreads();

    {
        int m  = tid >> 4;
        int c0 = (tid & 15) * 8;
        short8 own = *reinterpret_cast<const short8*>(
            hin + (size_t)(node0 + m) * HDIM + c0);
        *reinterpret_cast<short8*>(&hown[m][c0]) = own;

        float a0=0,a1=0,a2=0,a3=0,a4=0,a5=0,a6=0,a7=0;
        #pragma unroll
        for (int k = 0; k < KNN; ++k) {
            float wk = sw[m][k];
            short8 hv = *reinterpret_cast<const short8*>(
                hin + hbase + (size_t)sidx[m][k] * HDIM + c0);
            a0 = fmaf(wk, b2f(hv[0]), a0); a1 = fmaf(wk, b2f(hv[1]), a1);
            a2 = fmaf(wk, b2f(hv[2]), a2); a3 = fmaf(wk, b2f(hv[3]), a3);
            a4 = fmaf(wk, b2f(hv[4]), a4); a5 = fmaf(wk, b2f(hv[5]), a5);
            a6 = fmaf(wk, b2f(hv[6]), a6); a7 = fmaf(wk, b2f(hv[7]), a7);
        }
        short8 pk;
        pk[0]=f2b(a0); pk[1]=f2b(a1); pk[2]=f2b(a2); pk[3]=f2b(a3);
        pk[4]=f2b(a4); pk[5]=f2b(a5); pk[6]=f2b(a6); pk[7]=f2b(a7);
        *reinterpret_cast<short8*>(&aggb[m][c0]) = pk;
    }
    __syncthreads();

    f32x4 acc0 = {0.f,0.f,0.f,0.f}, acc1 = {0.f,0.f,0.f,0.f};
    #pragma unroll
    for (int ks = 0; ks < 4; ++ks) {
        short8 afrag = *reinterpret_cast<const short8*>(&aggb[l & 15][ks * 32 + (l >> 4) * 8]);
        acc0 = __builtin_amdgcn_mfma_f32_16x16x32_bf16(afrag, bfrag[0][ks], acc0, 0, 0, 0);
        acc1 = __builtin_amdgcn_mfma_f32_16x16x32_bf16(afrag, bfrag[1][ks], acc1, 0, 0, 0);
    }

    int g = l >> 4;
    int col0 = wv * 32 + (l & 15);
    int col1 = col0 + 16;
    float b0  = bias[col0],  b1  = bias[col1];
    float gm0 = gamma[col0], gm1 = gamma[col1];
    float bt0 = beta[col0],  bt1 = beta[col1];

    float y0[4], y1[4];
    #pragma unroll
    for (int r = 0; r < 4; ++r) {
        int rl = g * 4 + r;
        y0[r] = b2f(hown[rl][col0]) + fmaxf(acc0[r] + b0, 0.f);
        y1[r] = b2f(hown[rl][col1]) + fmaxf(acc1[r] + b1, 0.f);
    }

    #pragma unroll
    for (int r = 0; r < 4; ++r) {
        float ss = y0[r] + y1[r];
        float qq = y0[r] * y0[r] + y1[r] * y1[r];
        #pragma unroll
        for (int off = 1; off < 16; off <<= 1) {
            ss += __shfl_xor(ss, off, 64);
            qq += __shfl_xor(qq, off, 64);
        }
        if ((l & 15) == 0) { wred[wv][g * 4 + r][0] = ss; wred[wv][g * 4 + r][1] = qq; }
    }
    __syncthreads();

    #pragma unroll
    for (int r = 0; r < 4; ++r) {
        int row = g * 4 + r;
        float S = wred[0][row][0] + wred[1][row][0] + wred[2][row][0] + wred[3][row][0];
        float Q = wred[0][row][1] + wred[1][row][1] + wred[2][row][1] + wred[3][row][1];
        float mu  = S * (1.f / 128.f);
        float var = Q * (1.f / 128.f) - mu * mu;
        float rs  = rsqrtf(var + LN_EPS);
        size_t orow = (size_t)(node0 + row) * HDIM;
        float o0 = (y0[r] - mu) * rs * gm0 + bt0;
        float o1 = (y1[r] - mu) * rs * gm1 + bt1;
        if (OUT_F32) {
            hout_f[orow + col0] = o0;
            hout_f[orow + col1] = o1;
        } else {
            hout_b[orow + col0] = f2b(o0);
            hout_b[orow + col1] = f2b(o1);
        }
    }
}

// ---------------------------------------------------------------------------
extern "C" void kernel_launch(void* const* d_in, const int* in_sizes, int n_in,
                              void* d_out, int out_size, void* d_ws, size_t ws_size,
                              hipStream_t stream) {
    const float* node_emb = (const float*)d_in[0];
    const float* dist     = (const float*)d_in[1];
    const float* Ws       = (const float*)d_in[2];
    const float* bs       = (const float*)d_in[3];
    const float* gammas   = (const float*)d_in[4];
    const float* betas    = (const float*)d_in[5];
    float* out = (float*)d_out;

    char* ws = (char*)d_ws;
    int*   w_idx = (int*)  (ws + 0);                      // 640000 B
    float* w_val = (float*)(ws + 640000);                 // 640000 B
    __hip_bfloat16* WB = (__hip_bfloat16*)(ws + 1280000); // 65536 B (layers 1,2)
    short* h1b = (short*)(ws + 1345536);                  // 8192000 B
    short* h2b = (short*)(ws + 9537536);                  // 8192000 B

    // Dispatch 1: knn + layer 0 fused (+ WB pack for layers 1,2)
    knn_l0_kernel<<<NROWS / 4, 256, 0, stream>>>(
        dist, node_emb, Ws, bs, gammas, betas, WB, w_idx, w_val, h1b);

    const int nblocks = NROWS / 16;   // 2000

    // Dispatch 2: layer 1 (h1b -> h2b)
    layer_kernel_b<false><<<nblocks, 256, 0, stream>>>(h1b, w_idx, w_val,
        WB,          bs + HDIM,    gammas + HDIM,    betas + HDIM,    h2b, nullptr);
    // Dispatch 3: layer 2 (h2b -> out, fp32)
    layer_kernel_b<true><<<nblocks, 256, 0, stream>>>(h2b, w_idx, w_val,
        WB + 16384,  bs + 2*HDIM,  gammas + 2*HDIM,  betas + 2*HDIM,  nullptr, out);
}

// Round 15
// 103.328 us; speedup vs baseline: 2.5784x; 1.2139x over previous
//
#include <hip/hip_runtime.h>
#include <hip/hip_bf16.h>

#define BATCH 16
#define NNODE 2000
#define HDIM  128
#define KNN   5
#define NROWS (BATCH * NNODE)   // 32000
#define LN_EPS 1e-5f

typedef __attribute__((ext_vector_type(8))) short short8;
typedef __attribute__((ext_vector_type(4))) float f32x4;

__device__ __forceinline__ float b2f(short s) {
    unsigned int u = ((unsigned int)(unsigned short)s) << 16;
    return __uint_as_float(u);
}
__device__ __forceinline__ short f2b(float f) {
    __hip_bfloat16 h = __float2bfloat16(f);
    return *reinterpret_cast<short*>(&h);
}

__device__ __forceinline__ unsigned long long pack_di(float v, unsigned int idx) {
    unsigned int b = __float_as_uint(v);
    b = (b & 0x80000000u) ? ~b : (b | 0x80000000u);   // order-preserving
    return ((unsigned long long)b << 32) | idx;
}

// ---------------------------------------------------------------------------
// Kernel 1: knn + softmax (8000 blocks, one wave per row; ~64 VGPR so the
// HBM-bound phase keeps full occupancy — fusing anything heavier in here
// measurably hurts: rounds 10/14). Folded prep: Ws -> bf16 MFMA B-fragment
// order WB (blocks 0..23 only, negligible).
// ---------------------------------------------------------------------------
__global__ __launch_bounds__(256) void knn_prep_kernel(
    const float* __restrict__ dist,
    const float* __restrict__ Ws,
    __hip_bfloat16* __restrict__ WB,
    int* __restrict__ w_idx,
    float* __restrict__ w_val)
{
    int tg = blockIdx.x * 256 + threadIdx.x;

    // ---- weight prep: 6144 short8 entries (3 layers)
    if (tg < 3 * 2048) {
        int l    = tg >> 11;
        int r    = tg & 2047;
        int lane = r & 63;
        int ks   = (r >> 6) & 3;
        int ct   = (r >> 8) & 1;
        int wv   = (r >> 9) & 3;
        int col  = wv * 32 + ct * 16 + (lane & 15);
        int k0   = ks * 32 + (lane >> 4) * 8;
        const float* src = Ws + ((size_t)l << 14) + col * HDIM + k0;
        __hip_bfloat16* dst = WB + ((size_t)tg << 3);
        #pragma unroll
        for (int e = 0; e < 8; ++e) dst[e] = __float2bfloat16(src[e]);
    }

    // ---- knn for this wave's row
    int row  = blockIdx.x * 4 + (threadIdx.x >> 6);
    int lane = threadIdx.x & 63;
    const float4* r4 = reinterpret_cast<const float4*>(dist + (size_t)row * NNODE);

    unsigned long long pk0 = ~0ull, pk1 = ~0ull, pk2 = ~0ull, pk3 = ~0ull, pk4 = ~0ull;

    auto ins = [&](float d, int m) {
        unsigned long long key = pack_di(d, (unsigned int)m);
        if (key < pk4) {
            pk4 = key;
            unsigned long long t;
            if (pk4 < pk3) { t = pk3; pk3 = pk4; pk4 = t; }
            if (pk3 < pk2) { t = pk2; pk2 = pk3; pk3 = t; }
            if (pk2 < pk1) { t = pk1; pk1 = pk2; pk2 = t; }
            if (pk1 < pk0) { t = pk0; pk0 = pk1; pk1 = t; }
        }
    };

    // 500 float4s per row: lanes 0..51 handle 8, lanes 52..63 handle 7.
    float4 v[8];
    int base7 = lane + 448;
    bool has8 = base7 < (NNODE / 4);
    #pragma unroll
    for (int i = 0; i < 7; ++i) v[i] = r4[lane + 64 * i];
    v[7] = r4[has8 ? base7 : lane];     // in-row safe address

    #pragma unroll
    for (int i = 0; i < 7; ++i) {
        int base = (lane + 64 * i) * 4;
        ins(v[i].x, base); ins(v[i].y, base + 1);
        ins(v[i].z, base + 2); ins(v[i].w, base + 3);
    }
    if (has8) {
        int base = base7 * 4;
        ins(v[7].x, base); ins(v[7].y, base + 1);
        ins(v[7].z, base + 2); ins(v[7].w, base + 3);
    }

    unsigned long long chosen[KNN];
    #pragma unroll
    for (int r = 0; r < KNN; ++r) {
        unsigned long long mn = pk0;
        #pragma unroll
        for (int off = 32; off; off >>= 1) {
            unsigned long long o = __shfl_xor(mn, off, 64);
            if (o < mn) mn = o;
        }
        if (pk0 == mn) { pk0 = pk1; pk1 = pk2; pk2 = pk3; pk3 = pk4; pk4 = ~0ull; }
        chosen[r] = mn;
    }

    if (lane == 0) {
        float d[KNN]; int ix[KNN];
        #pragma unroll
        for (int r = 0; r < KNN; ++r) {
            unsigned int ub = (unsigned int)(chosen[r] >> 32);
            ub = (ub & 0x80000000u) ? (ub ^ 0x80000000u) : ~ub;
            d[r]  = __uint_as_float(ub);
            ix[r] = (int)(chosen[r] & 0xffffffffu);
        }
        float e[KNN]; float sum = 0.f;
        #pragma unroll
        for (int r = 0; r < KNN; ++r) { e[r] = expf(d[0] - d[r]); sum += e[r]; }
        float inv = 1.f / sum;
        #pragma unroll
        for (int r = 0; r < KNN; ++r) {
            w_idx[row * KNN + r] = ix[r];
            w_val[row * KNN + r] = e[r] * inv;
        }
    }
}

// ---------------------------------------------------------------------------
// Kernel 2: one GCN layer via MFMA.
// Block = 4 waves, 16 consecutive nodes (XCD-swizzled, bijective).
// IN_F32: gathers fp32 (layer 1, reads node_emb directly — no pre-convert);
// else bf16 h (one short8 per neighbor). fp32 agg math -> bf16 agg LDS;
// 8x mfma_16x16x32_bf16 per wave; fp32 residual (LDS) + LN epilogue;
// OUT_F32 selects fp32 final output vs bf16 intermediate.
// ---------------------------------------------------------------------------
template<bool IN_F32, bool OUT_F32>
__global__ __launch_bounds__(256) void layer_kernel_b(
    const float* __restrict__ hin_f,         // used when IN_F32
    const short* __restrict__ hin_b,         // used when !IN_F32
    const int*   __restrict__ w_idx,
    const float* __restrict__ w_val,
    const __hip_bfloat16* __restrict__ WB,   // fragment-ordered, this layer
    const float* __restrict__ bias,
    const float* __restrict__ gamma,
    const float* __restrict__ beta,
    short* __restrict__ hout_b,
    float* __restrict__ hout_f)
{
    __shared__ __hip_bfloat16 aggb[16][HDIM];   // 4 KB
    __shared__ float hown[16][HDIM];            // 8 KB (fp32 residual staging)
    __shared__ int   sidx[16][KNN];
    __shared__ float sw[16][KNN];
    __shared__ float wred[4][16][2];

    int tid = threadIdx.x;
    int wv  = tid >> 6;
    int l   = tid & 63;

    // XCD swizzle: 2000 blocks = 8 XCDs x 250; 2 batches per XCD (bijective).
    int bid = blockIdx.x;
    int x   = bid & 7;
    int j   = bid >> 3;
    int hi  = (j >= 125);
    int bsw = 2 * x + hi;
    int gid = bsw * 125 + (j - hi * 125);

    int node0 = gid * 16;
    size_t hbase = (size_t)bsw * NNODE * HDIM;

    // ---- B fragments: 8 coalesced short8 loads
    const short8* wb = reinterpret_cast<const short8*>(WB);
    short8 bfrag[2][4];
    #pragma unroll
    for (int ct = 0; ct < 2; ++ct)
        #pragma unroll
        for (int ks = 0; ks < 4; ++ks)
            bfrag[ct][ks] = wb[((wv * 2 + ct) * 4 + ks) * 64 + l];

    if (tid < 16 * KNN) {
        int m = tid / KNN, k = tid % KNN;
        sidx[m][k] = w_idx[(node0 + m) * KNN + k];
        sw[m][k]   = w_val[(node0 + m) * KNN + k];
    }
    __syncthreads();

    // ---- aggregation: thread t -> node m = t>>4, cols c0 = (t&15)*8
    {
        int m  = tid >> 4;
        int c0 = (tid & 15) * 8;
        float a0=0,a1=0,a2=0,a3=0,a4=0,a5=0,a6=0,a7=0;

        if constexpr (IN_F32) {
            const float4* po = reinterpret_cast<const float4*>(
                hin_f + (size_t)(node0 + m) * HDIM + c0);
            float4 o0 = po[0], o1 = po[1];
            *reinterpret_cast<float4*>(&hown[m][c0])     = o0;
            *reinterpret_cast<float4*>(&hown[m][c0 + 4]) = o1;

            #pragma unroll
            for (int k = 0; k < KNN; ++k) {
                float wk = sw[m][k];
                const float4* p = reinterpret_cast<const float4*>(
                    hin_f + hbase + (size_t)sidx[m][k] * HDIM + c0);
                float4 v0 = p[0], v1 = p[1];
                a0 = fmaf(wk, v0.x, a0); a1 = fmaf(wk, v0.y, a1);
                a2 = fmaf(wk, v0.z, a2); a3 = fmaf(wk, v0.w, a3);
                a4 = fmaf(wk, v1.x, a4); a5 = fmaf(wk, v1.y, a5);
                a6 = fmaf(wk, v1.z, a6); a7 = fmaf(wk, v1.w, a7);
            }
        } else {
            short8 own = *reinterpret_cast<const short8*>(
                hin_b + (size_t)(node0 + m) * HDIM + c0);
            float4 of0 = make_float4(b2f(own[0]), b2f(own[1]), b2f(own[2]), b2f(own[3]));
            float4 of1 = make_float4(b2f(own[4]), b2f(own[5]), b2f(own[6]), b2f(own[7]));
            *reinterpret_cast<float4*>(&hown[m][c0])     = of0;
            *reinterpret_cast<float4*>(&hown[m][c0 + 4]) = of1;

            #pragma unroll
            for (int k = 0; k < KNN; ++k) {
                float wk = sw[m][k];
                short8 hv = *reinterpret_cast<const short8*>(
                    hin_b + hbase + (size_t)sidx[m][k] * HDIM + c0);
                a0 = fmaf(wk, b2f(hv[0]), a0); a1 = fmaf(wk, b2f(hv[1]), a1);
                a2 = fmaf(wk, b2f(hv[2]), a2); a3 = fmaf(wk, b2f(hv[3]), a3);
                a4 = fmaf(wk, b2f(hv[4]), a4); a5 = fmaf(wk, b2f(hv[5]), a5);
                a6 = fmaf(wk, b2f(hv[6]), a6); a7 = fmaf(wk, b2f(hv[7]), a7);
            }
        }

        short8 pk;
        pk[0]=f2b(a0); pk[1]=f2b(a1); pk[2]=f2b(a2); pk[3]=f2b(a3);
        pk[4]=f2b(a4); pk[5]=f2b(a5); pk[6]=f2b(a6); pk[7]=f2b(a7);
        *reinterpret_cast<short8*>(&aggb[m][c0]) = pk;
    }
    __syncthreads();

    // ---- MFMA: per wave, C(16x32) over 4 k-steps
    f32x4 acc0 = {0.f,0.f,0.f,0.f}, acc1 = {0.f,0.f,0.f,0.f};
    #pragma unroll
    for (int ks = 0; ks < 4; ++ks) {
        short8 afrag = *reinterpret_cast<const short8*>(&aggb[l & 15][ks * 32 + (l >> 4) * 8]);
        acc0 = __builtin_amdgcn_mfma_f32_16x16x32_bf16(afrag, bfrag[0][ks], acc0, 0, 0, 0);
        acc1 = __builtin_amdgcn_mfma_f32_16x16x32_bf16(afrag, bfrag[1][ks], acc1, 0, 0, 0);
    }

    // ---- epilogue: y = h + relu(C + bias); LN over 128 cols
    int g = l >> 4;
    int col0 = wv * 32 + (l & 15);
    int col1 = col0 + 16;
    float b0  = bias[col0],  b1  = bias[col1];
    float gm0 = gamma[col0], gm1 = gamma[col1];
    float bt0 = beta[col0],  bt1 = beta[col1];

    float y0[4], y1[4];
    #pragma unroll
    for (int r = 0; r < 4; ++r) {
        int rl = g * 4 + r;
        y0[r] = hown[rl][col0] + fmaxf(acc0[r] + b0, 0.f);
        y1[r] = hown[rl][col1] + fmaxf(acc1[r] + b1, 0.f);
    }

    #pragma unroll
    for (int r = 0; r < 4; ++r) {
        float ss = y0[r] + y1[r];
        float qq = y0[r] * y0[r] + y1[r] * y1[r];
        #pragma unroll
        for (int off = 1; off < 16; off <<= 1) {
            ss += __shfl_xor(ss, off, 64);
            qq += __shfl_xor(qq, off, 64);
        }
        if ((l & 15) == 0) { wred[wv][g * 4 + r][0] = ss; wred[wv][g * 4 + r][1] = qq; }
    }
    __syncthreads();

    #pragma unroll
    for (int r = 0; r < 4; ++r) {
        int row = g * 4 + r;
        float S = wred[0][row][0] + wred[1][row][0] + wred[2][row][0] + wred[3][row][0];
        float Q = wred[0][row][1] + wred[1][row][1] + wred[2][row][1] + wred[3][row][1];
        float mu  = S * (1.f / 128.f);
        float var = Q * (1.f / 128.f) - mu * mu;
        float rs  = rsqrtf(var + LN_EPS);
        size_t orow = (size_t)(node0 + row) * HDIM;
        float o0 = (y0[r] - mu) * rs * gm0 + bt0;
        float o1 = (y1[r] - mu) * rs * gm1 + bt1;
        if (OUT_F32) {
            hout_f[orow + col0] = o0;
            hout_f[orow + col1] = o1;
        } else {
            hout_b[orow + col0] = f2b(o0);
            hout_b[orow + col1] = f2b(o1);
        }
    }
}

// ---------------------------------------------------------------------------
extern "C" void kernel_launch(void* const* d_in, const int* in_sizes, int n_in,
                              void* d_out, int out_size, void* d_ws, size_t ws_size,
                              hipStream_t stream) {
    const float* node_emb = (const float*)d_in[0];
    const float* dist     = (const float*)d_in[1];
    const float* Ws       = (const float*)d_in[2];
    const float* bs       = (const float*)d_in[3];
    const float* gammas   = (const float*)d_in[4];
    const float* betas    = (const float*)d_in[5];
    float* out = (float*)d_out;

    char* ws = (char*)d_ws;
    int*   w_idx = (int*)  (ws + 0);                      // 640000 B
    float* w_val = (float*)(ws + 640000);                 // 640000 B
    __hip_bfloat16* WB = (__hip_bfloat16*)(ws + 1280000); // 98304 B (3 layers)
    short* h1b = (short*)(ws + 1378304);                  // 8192000 B
    short* h2b = (short*)(ws + 9570304);                  // 8192000 B

    // Dispatch 1: knn + weight prep (lean: ~64 VGPR, full occupancy)
    knn_prep_kernel<<<NROWS / 4, 256, 0, stream>>>(dist, Ws, WB, w_idx, w_val);

    const int nblocks = NROWS / 16;   // 2000
    const int WL = 16384;             // bf16 elements per layer in WB

    // Dispatch 2: layer 1 reads fp32 node_emb directly -> bf16 h1b
    layer_kernel_b<true,  false><<<nblocks, 256, 0, stream>>>(
        node_emb, nullptr, w_idx, w_val,
        WB,          bs,           gammas,           betas,           h1b, nullptr);
    // Dispatch 3: layer 2 (bf16 -> bf16)
    layer_kernel_b<false, false><<<nblocks, 256, 0, stream>>>(
        nullptr, h1b, w_idx, w_val,
        WB + WL,     bs + HDIM,    gammas + HDIM,    betas + HDIM,    h2b, nullptr);
    // Dispatch 4: layer 3 (bf16 -> fp32 out)
    layer_kernel_b<false, true><<<nblocks, 256, 0, stream>>>(
        nullptr, h2b, w_idx, w_val,
        WB + 2*WL,   bs + 2*HDIM,  gammas + 2*HDIM,  betas + 2*HDIM,  nullptr, out);
}

// Round 16
// 100.165 us; speedup vs baseline: 2.6598x; 1.0316x over previous
//
#include <hip/hip_runtime.h>
#include <hip/hip_bf16.h>

#define BATCH 16
#define NNODE 2000
#define HDIM  128
#define KNN   5
#define NROWS (BATCH * NNODE)   // 32000
#define LN_EPS 1e-5f
#define AP 136                  // aggb row pad (bank-conflict fix)
#define HP 132                  // hown row pad

typedef __attribute__((ext_vector_type(8))) short short8;
typedef __attribute__((ext_vector_type(4))) float f32x4;

__device__ __forceinline__ float b2f(short s) {
    unsigned int u = ((unsigned int)(unsigned short)s) << 16;
    return __uint_as_float(u);
}
__device__ __forceinline__ short f2b(float f) {
    __hip_bfloat16 h = __float2bfloat16(f);
    return *reinterpret_cast<short*>(&h);
}

__device__ __forceinline__ unsigned long long pack_di(float v, unsigned int idx) {
    unsigned int b = __float_as_uint(v);
    b = (b & 0x80000000u) ? ~b : (b | 0x80000000u);   // order-preserving
    return ((unsigned long long)b << 32) | idx;
}

// ---------------------------------------------------------------------------
// Kernel 1: knn + softmax (8000 blocks, one wave per row; lean ~64 VGPR —
// fusing anything heavier in here measurably hurts: rounds 10/14).
// Folded prep: Ws -> bf16 MFMA B-fragment order WB (blocks 0..23).
// ---------------------------------------------------------------------------
__global__ __launch_bounds__(256) void knn_prep_kernel(
    const float* __restrict__ dist,
    const float* __restrict__ Ws,
    __hip_bfloat16* __restrict__ WB,
    int* __restrict__ w_idx,
    float* __restrict__ w_val)
{
    int tg = blockIdx.x * 256 + threadIdx.x;

    // ---- weight prep: 6144 short8 entries (3 layers)
    if (tg < 3 * 2048) {
        int l    = tg >> 11;
        int r    = tg & 2047;
        int lane = r & 63;
        int ks   = (r >> 6) & 3;
        int ct   = (r >> 8) & 1;
        int wv   = (r >> 9) & 3;
        int col  = wv * 32 + ct * 16 + (lane & 15);
        int k0   = ks * 32 + (lane >> 4) * 8;
        const float* src = Ws + ((size_t)l << 14) + col * HDIM + k0;
        __hip_bfloat16* dst = WB + ((size_t)tg << 3);
        #pragma unroll
        for (int e = 0; e < 8; ++e) dst[e] = __float2bfloat16(src[e]);
    }

    // ---- knn for this wave's row
    int row  = blockIdx.x * 4 + (threadIdx.x >> 6);
    int lane = threadIdx.x & 63;
    const float4* r4 = reinterpret_cast<const float4*>(dist + (size_t)row * NNODE);

    unsigned long long pk0 = ~0ull, pk1 = ~0ull, pk2 = ~0ull, pk3 = ~0ull, pk4 = ~0ull;

    auto ins = [&](float d, int m) {
        unsigned long long key = pack_di(d, (unsigned int)m);
        if (key < pk4) {
            pk4 = key;
            unsigned long long t;
            if (pk4 < pk3) { t = pk3; pk3 = pk4; pk4 = t; }
            if (pk3 < pk2) { t = pk2; pk2 = pk3; pk3 = t; }
            if (pk2 < pk1) { t = pk1; pk1 = pk2; pk2 = t; }
            if (pk1 < pk0) { t = pk0; pk0 = pk1; pk1 = t; }
        }
    };

    float4 v[8];
    int base7 = lane + 448;
    bool has8 = base7 < (NNODE / 4);
    #pragma unroll
    for (int i = 0; i < 7; ++i) v[i] = r4[lane + 64 * i];
    v[7] = r4[has8 ? base7 : lane];     // in-row safe address

    #pragma unroll
    for (int i = 0; i < 7; ++i) {
        int base = (lane + 64 * i) * 4;
        ins(v[i].x, base); ins(v[i].y, base + 1);
        ins(v[i].z, base + 2); ins(v[i].w, base + 3);
    }
    if (has8) {
        int base = base7 * 4;
        ins(v[7].x, base); ins(v[7].y, base + 1);
        ins(v[7].z, base + 2); ins(v[7].w, base + 3);
    }

    unsigned long long chosen[KNN];
    #pragma unroll
    for (int r = 0; r < KNN; ++r) {
        unsigned long long mn = pk0;
        #pragma unroll
        for (int off = 32; off; off >>= 1) {
            unsigned long long o = __shfl_xor(mn, off, 64);
            if (o < mn) mn = o;
        }
        if (pk0 == mn) { pk0 = pk1; pk1 = pk2; pk2 = pk3; pk3 = pk4; pk4 = ~0ull; }
        chosen[r] = mn;
    }

    if (lane == 0) {
        float d[KNN]; int ix[KNN];
        #pragma unroll
        for (int r = 0; r < KNN; ++r) {
            unsigned int ub = (unsigned int)(chosen[r] >> 32);
            ub = (ub & 0x80000000u) ? (ub ^ 0x80000000u) : ~ub;
            d[r]  = __uint_as_float(ub);
            ix[r] = (int)(chosen[r] & 0xffffffffu);
        }
        float e[KNN]; float sum = 0.f;
        #pragma unroll
        for (int r = 0; r < KNN; ++r) { e[r] = expf(d[0] - d[r]); sum += e[r]; }
        float inv = 1.f / sum;
        #pragma unroll
        for (int r = 0; r < KNN; ++r) {
            w_idx[row * KNN + r] = ix[r];
            w_val[row * KNN + r] = e[r] * inv;
        }
    }
}

// ---------------------------------------------------------------------------
// Kernel 2: one GCN layer via MFMA.
// Block = 4 waves, 16 consecutive nodes (XCD-swizzled, bijective).
// This round: (a) neighbor ids/weights straight to registers (no LDS stage,
// one less sync); (b) aggb padded [16][136] -> kills the 16-way ds_read_b128
// bank conflict; (c) hown padded [16][132]; (d) launch_bounds(256,4).
// ---------------------------------------------------------------------------
template<bool IN_F32, bool OUT_F32>
__global__ __launch_bounds__(256, 4) void layer_kernel_b(
    const float* __restrict__ hin_f,         // used when IN_F32
    const short* __restrict__ hin_b,         // used when !IN_F32
    const int*   __restrict__ w_idx,
    const float* __restrict__ w_val,
    const __hip_bfloat16* __restrict__ WB,   // fragment-ordered, this layer
    const float* __restrict__ bias,
    const float* __restrict__ gamma,
    const float* __restrict__ beta,
    short* __restrict__ hout_b,
    float* __restrict__ hout_f)
{
    __shared__ __hip_bfloat16 aggb[16][AP];     // 4.25 KB, padded
    __shared__ float hown[16][HP];              // 8.25 KB, padded
    __shared__ float wred[4][16][2];

    int tid = threadIdx.x;
    int wv  = tid >> 6;
    int l   = tid & 63;

    // XCD swizzle: 2000 blocks = 8 XCDs x 250; 2 batches per XCD (bijective).
    int bid = blockIdx.x;
    int x   = bid & 7;
    int j   = bid >> 3;
    int hi  = (j >= 125);
    int bsw = 2 * x + hi;
    int gid = bsw * 125 + (j - hi * 125);

    int node0 = gid * 16;
    size_t hbase = (size_t)bsw * NNODE * HDIM;

    int m  = tid >> 4;          // node within tile
    int c0 = (tid & 15) * 8;    // feature block

    // ---- earliest: neighbor ids/weights to registers (16 lanes/node
    // broadcast-coalesce) and own-row load — gather addresses resolve ASAP.
    int   nid[KNN];
    float nw [KNN];
    {
        const int*   wip = w_idx + (node0 + m) * KNN;
        const float* wvp = w_val + (node0 + m) * KNN;
        #pragma unroll
        for (int k = 0; k < KNN; ++k) { nid[k] = wip[k]; nw[k] = wvp[k]; }
    }

    // ---- B fragments: 8 coalesced short8 loads (independent, fill latency)
    const short8* wb = reinterpret_cast<const short8*>(WB);
    short8 bfrag[2][4];
    #pragma unroll
    for (int ct = 0; ct < 2; ++ct)
        #pragma unroll
        for (int ks = 0; ks < 4; ++ks)
            bfrag[ct][ks] = wb[((wv * 2 + ct) * 4 + ks) * 64 + l];

    // ---- own-row staging + gather-aggregate -> bf16 aggb
    {
        float a0=0,a1=0,a2=0,a3=0,a4=0,a5=0,a6=0,a7=0;

        if constexpr (IN_F32) {
            const float4* po = reinterpret_cast<const float4*>(
                hin_f + (size_t)(node0 + m) * HDIM + c0);
            float4 o0 = po[0], o1 = po[1];
            *reinterpret_cast<float4*>(&hown[m][c0])     = o0;
            *reinterpret_cast<float4*>(&hown[m][c0 + 4]) = o1;

            #pragma unroll
            for (int k = 0; k < KNN; ++k) {
                float wk = nw[k];
                const float4* p = reinterpret_cast<const float4*>(
                    hin_f + hbase + (size_t)nid[k] * HDIM + c0);
                float4 v0 = p[0], v1 = p[1];
                a0 = fmaf(wk, v0.x, a0); a1 = fmaf(wk, v0.y, a1);
                a2 = fmaf(wk, v0.z, a2); a3 = fmaf(wk, v0.w, a3);
                a4 = fmaf(wk, v1.x, a4); a5 = fmaf(wk, v1.y, a5);
                a6 = fmaf(wk, v1.z, a6); a7 = fmaf(wk, v1.w, a7);
            }
        } else {
            short8 own = *reinterpret_cast<const short8*>(
                hin_b + (size_t)(node0 + m) * HDIM + c0);
            float4 of0 = make_float4(b2f(own[0]), b2f(own[1]), b2f(own[2]), b2f(own[3]));
            float4 of1 = make_float4(b2f(own[4]), b2f(own[5]), b2f(own[6]), b2f(own[7]));
            *reinterpret_cast<float4*>(&hown[m][c0])     = of0;
            *reinterpret_cast<float4*>(&hown[m][c0 + 4]) = of1;

            #pragma unroll
            for (int k = 0; k < KNN; ++k) {
                float wk = nw[k];
                short8 hv = *reinterpret_cast<const short8*>(
                    hin_b + hbase + (size_t)nid[k] * HDIM + c0);
                a0 = fmaf(wk, b2f(hv[0]), a0); a1 = fmaf(wk, b2f(hv[1]), a1);
                a2 = fmaf(wk, b2f(hv[2]), a2); a3 = fmaf(wk, b2f(hv[3]), a3);
                a4 = fmaf(wk, b2f(hv[4]), a4); a5 = fmaf(wk, b2f(hv[5]), a5);
                a6 = fmaf(wk, b2f(hv[6]), a6); a7 = fmaf(wk, b2f(hv[7]), a7);
            }
        }

        short8 pk;
        pk[0]=f2b(a0); pk[1]=f2b(a1); pk[2]=f2b(a2); pk[3]=f2b(a3);
        pk[4]=f2b(a4); pk[5]=f2b(a5); pk[6]=f2b(a6); pk[7]=f2b(a7);
        *reinterpret_cast<short8*>(&aggb[m][c0]) = pk;
    }
    __syncthreads();

    // ---- MFMA: per wave, C(16x32) over 4 k-steps (padded-row reads)
    f32x4 acc0 = {0.f,0.f,0.f,0.f}, acc1 = {0.f,0.f,0.f,0.f};
    #pragma unroll
    for (int ks = 0; ks < 4; ++ks) {
        short8 afrag = *reinterpret_cast<const short8*>(
            &aggb[l & 15][ks * 32 + (l >> 4) * 8]);
        acc0 = __builtin_amdgcn_mfma_f32_16x16x32_bf16(afrag, bfrag[0][ks], acc0, 0, 0, 0);
        acc1 = __builtin_amdgcn_mfma_f32_16x16x32_bf16(afrag, bfrag[1][ks], acc1, 0, 0, 0);
    }

    // ---- epilogue: y = h + relu(C + bias); LN over 128 cols
    int g = l >> 4;
    int col0 = wv * 32 + (l & 15);
    int col1 = col0 + 16;
    float b0  = bias[col0],  b1  = bias[col1];
    float gm0 = gamma[col0], gm1 = gamma[col1];
    float bt0 = beta[col0],  bt1 = beta[col1];

    float y0[4], y1[4];
    #pragma unroll
    for (int r = 0; r < 4; ++r) {
        int rl = g * 4 + r;
        y0[r] = hown[rl][col0] + fmaxf(acc0[r] + b0, 0.f);
        y1[r] = hown[rl][col1] + fmaxf(acc1[r] + b1, 0.f);
    }

    #pragma unroll
    for (int r = 0; r < 4; ++r) {
        float ss = y0[r] + y1[r];
        float qq = y0[r] * y0[r] + y1[r] * y1[r];
        #pragma unroll
        for (int off = 1; off < 16; off <<= 1) {
            ss += __shfl_xor(ss, off, 64);
            qq += __shfl_xor(qq, off, 64);
        }
        if ((l & 15) == 0) { wred[wv][g * 4 + r][0] = ss; wred[wv][g * 4 + r][1] = qq; }
    }
    __syncthreads();

    #pragma unroll
    for (int r = 0; r < 4; ++r) {
        int row = g * 4 + r;
        float S = wred[0][row][0] + wred[1][row][0] + wred[2][row][0] + wred[3][row][0];
        float Q = wred[0][row][1] + wred[1][row][1] + wred[2][row][1] + wred[3][row][1];
        float mu  = S * (1.f / 128.f);
        float var = Q * (1.f / 128.f) - mu * mu;
        float rs  = rsqrtf(var + LN_EPS);
        size_t orow = (size_t)(node0 + row) * HDIM;
        float o0 = (y0[r] - mu) * rs * gm0 + bt0;
        float o1 = (y1[r] - mu) * rs * gm1 + bt1;
        if (OUT_F32) {
            hout_f[orow + col0] = o0;
            hout_f[orow + col1] = o1;
        } else {
            hout_b[orow + col0] = f2b(o0);
            hout_b[orow + col1] = f2b(o1);
        }
    }
}

// ---------------------------------------------------------------------------
extern "C" void kernel_launch(void* const* d_in, const int* in_sizes, int n_in,
                              void* d_out, int out_size, void* d_ws, size_t ws_size,
                              hipStream_t stream) {
    const float* node_emb = (const float*)d_in[0];
    const float* dist     = (const float*)d_in[1];
    const float* Ws       = (const float*)d_in[2];
    const float* bs       = (const float*)d_in[3];
    const float* gammas   = (const float*)d_in[4];
    const float* betas    = (const float*)d_in[5];
    float* out = (float*)d_out;

    char* ws = (char*)d_ws;
    int*   w_idx = (int*)  (ws + 0);                      // 640000 B
    float* w_val = (float*)(ws + 640000);                 // 640000 B
    __hip_bfloat16* WB = (__hip_bfloat16*)(ws + 1280000); // 98304 B (3 layers)
    short* h1b = (short*)(ws + 1378304);                  // 8192000 B
    short* h2b = (short*)(ws + 9570304);                  // 8192000 B

    // Dispatch 1: knn + weight prep (lean: full occupancy on HBM-bound phase)
    knn_prep_kernel<<<NROWS / 4, 256, 0, stream>>>(dist, Ws, WB, w_idx, w_val);

    const int nblocks = NROWS / 16;   // 2000
    const int WL = 16384;             // bf16 elements per layer in WB

    // Dispatch 2: layer 1 reads fp32 node_emb directly -> bf16 h1b
    layer_kernel_b<true,  false><<<nblocks, 256, 0, stream>>>(
        node_emb, nullptr, w_idx, w_val,
        WB,          bs,           gammas,           betas,           h1b, nullptr);
    // Dispatch 3: layer 2 (bf16 -> bf16)
    layer_kernel_b<false, false><<<nblocks, 256, 0, stream>>>(
        nullptr, h1b, w_idx, w_val,
        WB + WL,     bs + HDIM,    gammas + HDIM,    betas + HDIM,    h2b, nullptr);
    // Dispatch 4: layer 3 (bf16 -> fp32 out)
    layer_kernel_b<false, true><<<nblocks, 256, 0, stream>>>(
        nullptr, h2b, w_idx, w_val,
        WB + 2*WL,   bs + 2*HDIM,  gammas + 2*HDIM,  betas + 2*HDIM,  nullptr, out);
}